// Round 11
// baseline (175.352 us; speedup 1.0000x reference)
//
#include <hip/hip_runtime.h>
#include <math.h>

#define NUM_NODES 2000000
#define NUM_FLOPS 800000
#define NBX 168
#define NBY 480
#define NCK 8
#define NCE 8
#define NBINS (NBX * NBY)          // 80,640
#define YB_ROWS 10                 // y-bucket / tile granularity
#define NYB 48                     // y-buckets per column
// Column mass is NOT uniform: col 167 absorbs all cx>=167 -> ~6,070 expected.
#define CAPC 6720                  // per-column PRE-dup cap (worst col +8 sigma)
#define CAPR 9600                  // per-column POST-dup slots
#define SORT_IT 7                  // ceil(CAPC/1024)
#define W 2                        // columns owned per ff_main block
// Tile rows CLAMPED to [3,14]: rows 4..13 owned (y0..y0+9), rows 3 and 14 are
// shared garbage collectors for the 8 former pad rows. Clamp collisions only
// ever target garbage rows (owned rows are clamp fixed points); within-round
// address distinctness (addr == ke mod 64) is unaffected. 18->12 rows cuts
// the wave tile to 6KB -> 24.6KB/block -> 6 blocks/CU = 24 waves (was 16).
#define TROWS 12
#define TILE_F (TROWS * W * 64)    // 1,536 floats per wave-private tile (6 KB)
#define S_INVSQRT2 0.7071067811865476f
#define P1_FLOPS 2048              // flops per pass-1 block (was 4096)
#define P1_BLOCKS 391              // ceil(800000/2048)
#define P1_THREADS 512

// -------- workspace layout --------
// scale  : float [NBINS]                (322.6 KB)
// colcnt : int   [NBX]                  (672 B)
// bstart : int   [NBX*NYB]              (32.3 KB)
// bcnt   : int   [NBX*NYB]              (32.3 KB)
// rec    : Rec12 [NBX * CAPR]           (19.35 MB)   total ~19.76 MB < 20.97 MB cap

struct Rec12 { float cx, cy; int keby; };   // keby = (bx0<<15) | (by0<<6) | ke

// Branch-free erf, Abramowitz-Stegun 7.1.26 (max abs err 1.5e-7).
__device__ __forceinline__ float fast_erf(float x) {
    float ax = fabsf(x);
    float t = __builtin_amdgcn_rcpf(fmaf(0.3275911f, ax, 1.0f));
    float p = t * fmaf(t, fmaf(t, fmaf(t, fmaf(t, 1.061405429f, -1.453152027f),
                                       1.421413741f), -0.284496736f), 0.254829592f);
    float r = fmaf(-p, __expf(-ax * ax), 1.0f);
    return copysignf(r, x);
}

// -------- pass 1: column-grouped coalesced scatter --------
// 391 blocks x 512 thr (was 196x1024): ~1.5 blocks/CU spread + 27KB LDS
// allows multi-block residency; runs of ~12 recs/column (~146B, ~70% line
// utilization vs 19% for the R8 random scatter).
__global__ void __launch_bounds__(P1_THREADS, 8)
ff_fill(const float* __restrict__ pos,
        const float* __restrict__ nsx,
        const float* __restrict__ nsy,
        const int* __restrict__ fi,
        const int* __restrict__ cs,
        int* __restrict__ colcnt,
        Rec12* __restrict__ rec,
        float* __restrict__ out) {
    __shared__ int hist[NBX];
    __shared__ int ofs[NBX];
    __shared__ int gbase[NBX];
    __shared__ int sc[NBX];
    __shared__ int tot_s;
    __shared__ Rec12 staged[P1_FLOPS];        // 24.6 KB
    int tid = threadIdx.x;
    int f0 = blockIdx.x * P1_FLOPS;

    // fused: zero the output array
    for (int g = blockIdx.x * P1_THREADS + tid; g < NUM_NODES; g += P1_BLOCKS * P1_THREADS)
        out[g] = 0.f;

    for (int j = tid; j < NBX; j += P1_THREADS) hist[j] = 0;
    __syncthreads();

    int colq[4], r1q[4], kebyq[4];
    float cxq[4], cyq[4];
    bool vq[4];
#pragma unroll
    for (int q = 0; q < 4; ++q) {
        int f = f0 + q * P1_THREADS + tid;
        bool valid = f < NUM_FLOPS;
        vq[q] = valid; colq[q] = 0; r1q[q] = 0; kebyq[q] = 0; cxq[q] = 0.f; cyq[q] = 0.f;
        if (valid) {
            int i = fi[f];
            float cx = pos[i] + 0.5f * nsx[i];
            float cy = pos[NUM_NODES + i] + 0.5f * nsy[i];
            int bx0 = (int)floorf(cx); bx0 = bx0 < 0 ? 0 : (bx0 > NBX - 1 ? NBX - 1 : bx0);
            int by0 = (int)floorf(cy); by0 = by0 < 0 ? 0 : (by0 > NBY - 1 ? NBY - 1 : by0);
            int2 cc = ((const int2*)cs)[f];
            int ke = cc.x * NCE + cc.y;
            colq[q] = bx0; cxq[q] = cx; cyq[q] = cy;
            kebyq[q] = (bx0 << 15) | (by0 << 6) | ke;
            r1q[q] = atomicAdd(&hist[bx0], 1);
        }
    }
    __syncthreads();
    // exclusive scan of hist[168] (Hillis-Steele)
    if (tid < NBX) sc[tid] = hist[tid];
    __syncthreads();
    for (int d = 1; d < NBX; d <<= 1) {
        int v2 = 0;
        if (tid < NBX && tid >= d) v2 = sc[tid - d];
        __syncthreads();
        if (tid < NBX) sc[tid] += v2;
        __syncthreads();
    }
    if (tid < NBX) {
        ofs[tid] = sc[tid] - hist[tid];
        int nn = hist[tid];
        gbase[tid] = nn ? atomicAdd(&colcnt[tid], nn) : 0;   // one atomic per (block,col)
    }
    if (tid == 0) tot_s = sc[NBX - 1];
    __syncthreads();
#pragma unroll
    for (int q = 0; q < 4; ++q)
        if (vq[q]) {
            Rec12 v; v.cx = cxq[q]; v.cy = cyq[q]; v.keby = kebyq[q];
            staged[ofs[colq[q]] + r1q[q]] = v;
        }
    __syncthreads();
    // coalesced copy-out: consecutive t -> same column -> consecutive slots
    for (int t = tid; t < tot_s; t += P1_THREADS) {
        Rec12 v = staged[t];
        int c = (v.keby >> 15) & 255;
        int slot = gbase[c] + (t - ofs[c]);
        if (slot < CAPC) rec[(size_t)c * CAPR + slot] = v;
    }
}

// -------- pass 2: per-column yb-sort (+ halo dup) with exact offsets --------
__global__ void __launch_bounds__(1024)
ff_sort(const int* __restrict__ colcnt,
        Rec12* __restrict__ rec,
        int* __restrict__ bstart,
        int* __restrict__ bcnt) {
    __shared__ Rec12 staged[CAPC];            // 80.6 KB
    __shared__ unsigned short perm[CAPR];     // 19.2 KB
    __shared__ int hist[NYB];
    __shared__ int ofs[NYB + 1];
    int c = blockIdx.x;
    int tid = threadIdx.x;
    int n = colcnt[c]; n = n < CAPC ? n : CAPC;
    Rec12* col = rec + (size_t)c * CAPR;
    for (int t = tid; t < n; t += 1024) staged[t] = col[t];
    if (tid < NYB) hist[tid] = 0;
    __syncthreads();

    int sP[SORT_IT], sH[SORT_IT], ybq[SORT_IT], ybhq[SORT_IT];   // regs, const-idx
#pragma unroll
    for (int it = 0; it < SORT_IT; ++it) {
        int t = it * 1024 + tid;
        sP[it] = 0; sH[it] = 0; ybq[it] = 0; ybhq[it] = -1;
        if (t < n) {
            int by0 = (staged[t].keby >> 6) & 511;
            int yb = by0 / YB_ROWS;
            int rlo = by0 - yb * YB_ROWS;
            ybq[it] = yb;
            sP[it] = atomicAdd(&hist[yb], 1);
            int ybh = (rlo <= 1 && yb > 0) ? yb - 1
                    : ((rlo >= YB_ROWS - 2 && yb < NYB - 1) ? yb + 1 : -1);
            ybhq[it] = ybh;
            if (ybh >= 0) sH[it] = atomicAdd(&hist[ybh], 1);
        }
    }
    __syncthreads();
    if (tid == 0) {
        int s = 0;
        for (int g = 0; g < NYB; ++g) { ofs[g] = s; s += hist[g]; }
        ofs[NYB] = s;
    }
    __syncthreads();
#pragma unroll
    for (int it = 0; it < SORT_IT; ++it) {
        int t = it * 1024 + tid;
        if (t < n) {
            int ip = ofs[ybq[it]] + sP[it];
            if (ip < CAPR) perm[ip] = (unsigned short)t;
            if (ybhq[it] >= 0) {
                int ih = ofs[ybhq[it]] + sH[it];
                if (ih < CAPR) perm[ih] = (unsigned short)t;
            }
        }
    }
    __syncthreads();
    int m = ofs[NYB]; m = m < CAPR ? m : CAPR;
    for (int t = tid; t < m; t += 1024) col[t] = staged[perm[t]];   // coalesced
    if (tid < NYB) {
        int s0 = ofs[tid];             s0 = s0 < CAPR ? s0 : CAPR;
        int e0 = ofs[tid] + hist[tid]; e0 = e0 < CAPR ? e0 : CAPR;
        bstart[c * NYB + tid] = c * CAPR + s0;
        bcnt[c * NYB + tid]   = e0 - s0;
    }
}

// -------- main: R10 core + clamped 12-row tile, 6 blocks/CU --------
__global__ void __launch_bounds__(256, 6)
ff_main(const int* __restrict__ bstart,
        const int* __restrict__ bcnt,
        const Rec12* __restrict__ rec,
        float* __restrict__ scale) {
    __shared__ __align__(16) float sh[4 * TILE_F];   // 24,576 B
    int tid = threadIdx.x;
    int wv = tid >> 6, lane = tid & 63;
    float* wtile = sh + wv * TILE_F;
    int c0 = blockIdx.x * W;
    int yb = blockIdx.y;
    int y0 = yb * YB_ROWS;

    for (int j = tid; j < TILE_F; j += 256)          // 4*TILE_F floats = TILE_F float4
        ((float4*)sh)[j] = make_float4(0.f, 0.f, 0.f, 0.f);
    __syncthreads();

    int c_lo = c0 - 2 < 0 ? 0 : c0 - 2;
    int c_hi = c0 + W + 1 > NBX - 1 ? NBX - 1 : c0 + W + 1;
    int nb = c_hi - c_lo + 1;                        // 4..6
    int start[7], sb6[6];
    start[0] = 0;
#pragma unroll
    for (int k = 0; k < 6; ++k) {
        int nrec = 0, sbv = 0;
        if (k < nb) {
            int b = (c_lo + k) * NYB + yb;
            nrec = bcnt[b]; sbv = bstart[b];
        }
        sb6[k] = sbv;
        start[k + 1] = start[k] + nrec;
    }
    int tot = start[6];

    for (int idx = tid; idx < tot; idx += 256) {
        int k = 0, off = idx, base = sb6[0];
#pragma unroll
        for (int t = 1; t < 6; ++t) {
            bool g = idx >= start[t];
            k = g ? t : k; off = g ? idx - start[t] : off; base = g ? sb6[t] : base;
        }
        Rec12 v = rec[(size_t)(base + off)];
        float cx = v.cx, cy = v.cy;
        int ke  = v.keby & 63;
        int by0 = (v.keby >> 6) & 511;
        int bx0 = c_lo + k;                          // bucket column == record's bx0
        float ex[W + 1], ey[6];
#pragma unroll
        for (int i = 0; i <= W; ++i)
            ex[i] = fast_erf(((float)(c0 + i) - cx) * S_INVSQRT2);
#pragma unroll
        for (int j = 0; j < 6; ++j)
            ey[j] = fast_erf(((float)(by0 - 2 + j) - cy) * S_INVSQRT2);
        float dyq[5];
#pragma unroll
        for (int j = 0; j < 5; ++j) dyq[j] = ey[j + 1] - ey[j];
        float dxq[W];
#pragma unroll
        for (int i = 0; i < W; ++i) {
            int col = c0 + i;
            float mm = (col >= bx0 - 2 && col <= bx0 + 2) ? 1.f : 0.f;
            dxq[i] = 0.25f * (ex[i + 1] - ex[i]) * mm;
        }
        int rr0 = by0 - y0 + 2;                      // in [0,13]
        // clamped tile row offsets (floats): row tr-3 in [0,11]; garbage
        // rows 0 and 11 absorb clamped pads (values never read)
        int ro[5];
#pragma unroll
        for (int j = 0; j < 5; ++j) {
            int tr = rr0 + j;
            tr = tr < 3 ? 3 : (tr > 14 ? 14 : tr);   // v_med3-style clamp
            ro[j] = (tr - 3) * (W * 64);
        }

        unsigned long long peers = __ballot(1);
#pragma unroll
        for (int b = 0; b < 6; ++b) {
            unsigned long long bl = __ballot((ke >> b) & 1);
            peers &= ((ke >> b) & 1) ? bl : ~bl;
        }
        int rank = (int)__popcll(peers & ((1ull << lane) - 1ull));

        for (int r = 0;; ++r) {                      // ke-rank-rounds (R7-proven)
            if (!__ballot(rank == r)) break;
            if (rank == r) {
                float* t0 = wtile + ke;
                // NOTE: a lane's clamped rows may alias each other (e.g.
                // rr0=0 -> ro[0..3] identical). Read-all/write-all then loses
                // all but one add — ONLY on garbage rows, which is fine.
                float a0 = t0[ro[0]], a1 = t0[ro[1]], a2 = t0[ro[2]],
                      a3 = t0[ro[3]], a4 = t0[ro[4]];
                float b0 = t0[ro[0] + 64], b1 = t0[ro[1] + 64], b2 = t0[ro[2] + 64],
                      b3 = t0[ro[3] + 64], b4 = t0[ro[4] + 64];
                a0 = fmaf(dxq[0], dyq[0], a0); b0 = fmaf(dxq[1], dyq[0], b0);
                a1 = fmaf(dxq[0], dyq[1], a1); b1 = fmaf(dxq[1], dyq[1], b1);
                a2 = fmaf(dxq[0], dyq[2], a2); b2 = fmaf(dxq[1], dyq[2], b2);
                a3 = fmaf(dxq[0], dyq[3], a3); b3 = fmaf(dxq[1], dyq[3], b3);
                a4 = fmaf(dxq[0], dyq[4], a4); b4 = fmaf(dxq[1], dyq[4], b4);
                t0[ro[0]] = a0; t0[ro[1]] = a1; t0[ro[2]] = a2;
                t0[ro[3]] = a3; t0[ro[4]] = a4;
                t0[ro[0] + 64] = b0; t0[ro[1] + 64] = b1; t0[ro[2] + 64] = b2;
                t0[ro[3] + 64] = b3; t0[ro[4] + 64] = b4;
            }
            asm volatile("s_waitcnt lgkmcnt(0)" ::: "memory");
        }
    }
    __syncthreads();

    // fused 4-way tile merge + quantization reduce; owned rows = tile rows 1..10
    if (tid < YB_ROWS * W) {
        int rl = tid >> 1, cl = tid & 1;
        int off = (rl + 1) * (W * 64) + cl * 64;
        float tot2 = 0.f, halves = 0.f;
#pragma unroll
        for (int ck = 0; ck < NCK; ++ck) {
            float q = 0.f;
#pragma unroll
            for (int h2 = 0; h2 < 2; ++h2) {
                float4 d = make_float4(0.f, 0.f, 0.f, 0.f);
#pragma unroll
                for (int w2 = 0; w2 < 4; ++w2) {
                    float4 e = *(const float4*)(sh + w2 * TILE_F + off + ck * 8 + h2 * 4);
                    d.x += e.x; d.y += e.y; d.z += e.z; d.w += e.w;
                }
                tot2 += d.x + d.y + d.z + d.w;
                q += ceilf(d.x * 0.25f) + ceilf(d.y * 0.25f) +
                     ceilf(d.z * 0.25f) + ceilf(d.w * 0.25f);
            }
            halves += ceilf(0.5f * q);
        }
        float slices = ceilf(0.5f * halves);
        scale[(c0 + cl) * NBY + y0 + rl] = (tot2 > 0.f) ? (slices / fmaxf(tot2, 1e-12f)) : 0.f;
    }
}

__global__ void ff_gather(const float* __restrict__ pos,
                          const float* __restrict__ nsx,
                          const float* __restrict__ nsy,
                          const int* __restrict__ fi,
                          const float* __restrict__ scale,
                          float* __restrict__ out) {
    int f = blockIdx.x * blockDim.x + threadIdx.x;
    if (f >= NUM_FLOPS) return;
    int i = fi[f];
    float cx = pos[i] + 0.5f * nsx[i];
    float cy = pos[NUM_NODES + i] + 0.5f * nsy[i];
    int bx0 = (int)floorf(cx); bx0 = bx0 < 0 ? 0 : (bx0 > NBX - 1 ? NBX - 1 : bx0);
    int by0 = (int)floorf(cy); by0 = by0 < 0 ? 0 : (by0 > NBY - 1 ? NBY - 1 : by0);
    out[i] = scale[bx0 * NBY + by0];
}

extern "C" void kernel_launch(void* const* d_in, const int* in_sizes, int n_in,
                              void* d_out, int out_size, void* d_ws, size_t ws_size,
                              hipStream_t stream) {
    const float* pos = (const float*)d_in[0];
    const float* nsx = (const float*)d_in[1];
    const float* nsy = (const float*)d_in[2];
    const int*   fi  = (const int*)d_in[3];
    const int*   cs  = (const int*)d_in[4];
    float* out = (float*)d_out;

    float* scale  = (float*)d_ws;
    int*   colcnt = (int*)(scale + NBINS);
    int*   bstart = colcnt + NBX;
    int*   bcnt   = bstart + NBX * NYB;
    Rec12* rec    = (Rec12*)(bcnt + NBX * NYB);

    hipMemsetAsync(colcnt, 0, NBX * sizeof(int), stream);

    ff_fill<<<P1_BLOCKS, P1_THREADS, 0, stream>>>(pos, nsx, nsy, fi, cs, colcnt, rec, out);
    ff_sort<<<NBX, 1024, 0, stream>>>(colcnt, rec, bstart, bcnt);
    ff_main<<<dim3(NBX / W, NYB), 256, 0, stream>>>(bstart, bcnt, rec, scale);
    ff_gather<<<(NUM_FLOPS + 255) / 256, 256, 0, stream>>>(pos, nsx, nsy, fi, scale, out);
}

// Round 12
// 166.253 us; speedup vs baseline: 1.0547x; 1.0547x over previous
//
#include <hip/hip_runtime.h>
#include <math.h>

#define NUM_NODES 2000000
#define NUM_FLOPS 800000
#define NBX 168
#define NBY 480
#define NCK 8
#define NCE 8
#define NBINS (NBX * NBY)          // 80,640
#define YB_ROWS 10                 // y-bucket / tile granularity
#define NYB 48                     // y-buckets per column
// Column mass is NOT uniform: col 167 absorbs all cx>=167 -> ~6,070 expected.
#define CAPC 6720                  // per-column PRE-dup cap (worst col +8 sigma)
#define CAPR 9600                  // per-column POST-dup slots
#define SORT_IT 7                  // ceil(CAPC/1024)
#define W 2                        // columns owned per ff_main block
// Tile rows CLAMPED to [3,14]: rows 4..13 owned, rows 3/14 are shared garbage
// collectors (values never read; clamp fixed-points are exactly the owned
// rows; within-round addr==ke mod 64 distinctness unaffected). 6KB/wave.
#define TROWS 12
#define TILE_F (TROWS * W * 64)    // 1,536 floats per wave-private tile (6 KB)
#define S_INVSQRT2 0.7071067811865476f
#define P1_FLOPS 4096              // flops per pass-1 block (R10 config)
#define P1_BLOCKS 196              // ceil(800000/4096)

// -------- workspace layout --------
// scale  : float [NBINS]                (322.6 KB)
// colcnt : int   [NBX]                  (672 B)
// bstart : int   [NBX*NYB]              (32.3 KB)
// bcnt   : int   [NBX*NYB]              (32.3 KB)
// rec    : Rec12 [NBX * CAPR]           (19.35 MB)   total ~19.76 MB < 20.97 MB cap

struct Rec12 { float cx, cy; int keby; };   // keby = (bx0<<15) | (by0<<6) | ke

// Branch-free erf, Abramowitz-Stegun 7.1.26 (max abs err 1.5e-7).
__device__ __forceinline__ float fast_erf(float x) {
    float ax = fabsf(x);
    float t = __builtin_amdgcn_rcpf(fmaf(0.3275911f, ax, 1.0f));
    float p = t * fmaf(t, fmaf(t, fmaf(t, fmaf(t, 1.061405429f, -1.453152027f),
                                       1.421413741f), -0.284496736f), 0.254829592f);
    float r = fmaf(-p, __expf(-ax * ax), 1.0f);
    return copysignf(r, x);
}

// -------- pass 1: column-grouped coalesced scatter (R10 config) --------
// R8 counters: random 12B scatter = 63MB writebacks (19% line util) = 64us.
// Block-level column sort -> runs of ~24 recs (~290B, ~80% util).
// R11 lesson: 391x512 + launch-bounds re-grid cost +13us — reverted.
__global__ void __launch_bounds__(1024)
ff_fill(const float* __restrict__ pos,
        const float* __restrict__ nsx,
        const float* __restrict__ nsy,
        const int* __restrict__ fi,
        const int* __restrict__ cs,
        int* __restrict__ colcnt,
        Rec12* __restrict__ rec,
        float* __restrict__ out) {
    __shared__ int hist[NBX];
    __shared__ int ofs[NBX];
    __shared__ int gbase[NBX];
    __shared__ int sc[NBX];
    __shared__ int tot_s;
    __shared__ Rec12 staged[P1_FLOPS];        // 49.2 KB
    int tid = threadIdx.x;
    int f0 = blockIdx.x * P1_FLOPS;

    // fused: zero the output array
    for (int g = blockIdx.x * 1024 + tid; g < NUM_NODES; g += P1_BLOCKS * 1024)
        out[g] = 0.f;

    for (int j = tid; j < NBX; j += 1024) hist[j] = 0;
    __syncthreads();

    int colq[4], r1q[4], kebyq[4];
    float cxq[4], cyq[4];
    bool vq[4];
#pragma unroll
    for (int q = 0; q < 4; ++q) {
        int f = f0 + q * 1024 + tid;
        bool valid = f < NUM_FLOPS;
        vq[q] = valid; colq[q] = 0; r1q[q] = 0; kebyq[q] = 0; cxq[q] = 0.f; cyq[q] = 0.f;
        if (valid) {
            int i = fi[f];
            float cx = pos[i] + 0.5f * nsx[i];
            float cy = pos[NUM_NODES + i] + 0.5f * nsy[i];
            int bx0 = (int)floorf(cx); bx0 = bx0 < 0 ? 0 : (bx0 > NBX - 1 ? NBX - 1 : bx0);
            int by0 = (int)floorf(cy); by0 = by0 < 0 ? 0 : (by0 > NBY - 1 ? NBY - 1 : by0);
            int2 cc = ((const int2*)cs)[f];
            int ke = cc.x * NCE + cc.y;
            colq[q] = bx0; cxq[q] = cx; cyq[q] = cy;
            kebyq[q] = (bx0 << 15) | (by0 << 6) | ke;
            r1q[q] = atomicAdd(&hist[bx0], 1);
        }
    }
    __syncthreads();
    // exclusive scan of hist[168] (Hillis-Steele)
    if (tid < NBX) sc[tid] = hist[tid];
    __syncthreads();
    for (int d = 1; d < NBX; d <<= 1) {
        int v2 = 0;
        if (tid < NBX && tid >= d) v2 = sc[tid - d];
        __syncthreads();
        if (tid < NBX) sc[tid] += v2;
        __syncthreads();
    }
    if (tid < NBX) {
        ofs[tid] = sc[tid] - hist[tid];
        int nn = hist[tid];
        gbase[tid] = nn ? atomicAdd(&colcnt[tid], nn) : 0;   // one atomic per (block,col)
    }
    if (tid == 0) tot_s = sc[NBX - 1];
    __syncthreads();
#pragma unroll
    for (int q = 0; q < 4; ++q)
        if (vq[q]) {
            Rec12 v; v.cx = cxq[q]; v.cy = cyq[q]; v.keby = kebyq[q];
            staged[ofs[colq[q]] + r1q[q]] = v;
        }
    __syncthreads();
    // coalesced copy-out: consecutive t -> same column -> consecutive slots
    for (int t = tid; t < tot_s; t += 1024) {
        Rec12 v = staged[t];
        int c = (v.keby >> 15) & 255;
        int slot = gbase[c] + (t - ofs[c]);
        if (slot < CAPC) rec[(size_t)c * CAPR + slot] = v;
    }
}

// -------- pass 2: per-column yb-sort (+ halo dup) with exact offsets --------
__global__ void __launch_bounds__(1024)
ff_sort(const int* __restrict__ colcnt,
        Rec12* __restrict__ rec,
        int* __restrict__ bstart,
        int* __restrict__ bcnt) {
    __shared__ Rec12 staged[CAPC];            // 80.6 KB
    __shared__ unsigned short perm[CAPR];     // 19.2 KB
    __shared__ int hist[NYB];
    __shared__ int ofs[NYB + 1];
    int c = blockIdx.x;
    int tid = threadIdx.x;
    int n = colcnt[c]; n = n < CAPC ? n : CAPC;
    Rec12* col = rec + (size_t)c * CAPR;
    for (int t = tid; t < n; t += 1024) staged[t] = col[t];
    if (tid < NYB) hist[tid] = 0;
    __syncthreads();

    int sP[SORT_IT], sH[SORT_IT], ybq[SORT_IT], ybhq[SORT_IT];   // regs, const-idx
#pragma unroll
    for (int it = 0; it < SORT_IT; ++it) {
        int t = it * 1024 + tid;
        sP[it] = 0; sH[it] = 0; ybq[it] = 0; ybhq[it] = -1;
        if (t < n) {
            int by0 = (staged[t].keby >> 6) & 511;
            int yb = by0 / YB_ROWS;
            int rlo = by0 - yb * YB_ROWS;
            ybq[it] = yb;
            sP[it] = atomicAdd(&hist[yb], 1);
            int ybh = (rlo <= 1 && yb > 0) ? yb - 1
                    : ((rlo >= YB_ROWS - 2 && yb < NYB - 1) ? yb + 1 : -1);
            ybhq[it] = ybh;
            if (ybh >= 0) sH[it] = atomicAdd(&hist[ybh], 1);
        }
    }
    __syncthreads();
    if (tid == 0) {
        int s = 0;
        for (int g = 0; g < NYB; ++g) { ofs[g] = s; s += hist[g]; }
        ofs[NYB] = s;
    }
    __syncthreads();
#pragma unroll
    for (int it = 0; it < SORT_IT; ++it) {
        int t = it * 1024 + tid;
        if (t < n) {
            int ip = ofs[ybq[it]] + sP[it];
            if (ip < CAPR) perm[ip] = (unsigned short)t;
            if (ybhq[it] >= 0) {
                int ih = ofs[ybhq[it]] + sH[it];
                if (ih < CAPR) perm[ih] = (unsigned short)t;
            }
        }
    }
    __syncthreads();
    int m = ofs[NYB]; m = m < CAPR ? m : CAPR;
    for (int t = tid; t < m; t += 1024) col[t] = staged[perm[t]];   // coalesced
    if (tid < NYB) {
        int s0 = ofs[tid];             s0 = s0 < CAPR ? s0 : CAPR;
        int e0 = ofs[tid] + hist[tid]; e0 = e0 < CAPR ? e0 : CAPR;
        bstart[c * NYB + tid] = c * CAPR + s0;
        bcnt[c * NYB + tid]   = e0 - s0;
    }
}

// -------- main: clamped 12-row tile; launch_bounds(256,4) so the compiler
// keeps VGPR=56 (R11's (256,6) forced VGPR 40 -> 7MB scratch-spill traffic,
// visible as WRITE_SIZE 0.5->7MB). Residency comes from LDS: 24.6KB -> 6
// blocks/CU at runtime regardless of the hint. --------
__global__ void __launch_bounds__(256, 4)
ff_main(const int* __restrict__ bstart,
        const int* __restrict__ bcnt,
        const Rec12* __restrict__ rec,
        float* __restrict__ scale) {
    __shared__ __align__(16) float sh[4 * TILE_F];   // 24,576 B
    int tid = threadIdx.x;
    int wv = tid >> 6, lane = tid & 63;
    float* wtile = sh + wv * TILE_F;
    int c0 = blockIdx.x * W;
    int yb = blockIdx.y;
    int y0 = yb * YB_ROWS;

    for (int j = tid; j < TILE_F; j += 256)          // 4*TILE_F floats = TILE_F float4
        ((float4*)sh)[j] = make_float4(0.f, 0.f, 0.f, 0.f);
    __syncthreads();

    int c_lo = c0 - 2 < 0 ? 0 : c0 - 2;
    int c_hi = c0 + W + 1 > NBX - 1 ? NBX - 1 : c0 + W + 1;
    int nb = c_hi - c_lo + 1;                        // 4..6
    int start[7], sb6[6];
    start[0] = 0;
#pragma unroll
    for (int k = 0; k < 6; ++k) {
        int nrec = 0, sbv = 0;
        if (k < nb) {
            int b = (c_lo + k) * NYB + yb;
            nrec = bcnt[b]; sbv = bstart[b];
        }
        sb6[k] = sbv;
        start[k + 1] = start[k] + nrec;
    }
    int tot = start[6];

    for (int idx = tid; idx < tot; idx += 256) {
        int k = 0, off = idx, base = sb6[0];
#pragma unroll
        for (int t = 1; t < 6; ++t) {
            bool g = idx >= start[t];
            k = g ? t : k; off = g ? idx - start[t] : off; base = g ? sb6[t] : base;
        }
        Rec12 v = rec[(size_t)(base + off)];
        float cx = v.cx, cy = v.cy;
        int ke  = v.keby & 63;
        int by0 = (v.keby >> 6) & 511;
        int bx0 = c_lo + k;                          // bucket column == record's bx0
        float ex[W + 1], ey[6];
#pragma unroll
        for (int i = 0; i <= W; ++i)
            ex[i] = fast_erf(((float)(c0 + i) - cx) * S_INVSQRT2);
#pragma unroll
        for (int j = 0; j < 6; ++j)
            ey[j] = fast_erf(((float)(by0 - 2 + j) - cy) * S_INVSQRT2);
        float dyq[5];
#pragma unroll
        for (int j = 0; j < 5; ++j) dyq[j] = ey[j + 1] - ey[j];
        float dxq[W];
#pragma unroll
        for (int i = 0; i < W; ++i) {
            int col = c0 + i;
            float mm = (col >= bx0 - 2 && col <= bx0 + 2) ? 1.f : 0.f;
            dxq[i] = 0.25f * (ex[i + 1] - ex[i]) * mm;
        }
        int rr0 = by0 - y0 + 2;                      // in [0,13]
        int ro[5];
#pragma unroll
        for (int j = 0; j < 5; ++j) {
            int tr = rr0 + j;
            tr = tr < 3 ? 3 : (tr > 14 ? 14 : tr);   // clamp into [3,14]
            ro[j] = (tr - 3) * (W * 64);
        }

        unsigned long long peers = __ballot(1);
#pragma unroll
        for (int b = 0; b < 6; ++b) {
            unsigned long long bl = __ballot((ke >> b) & 1);
            peers &= ((ke >> b) & 1) ? bl : ~bl;
        }
        int rank = (int)__popcll(peers & ((1ull << lane) - 1ull));

        for (int r = 0;; ++r) {                      // ke-rank-rounds (R7-proven)
            if (!__ballot(rank == r)) break;
            if (rank == r) {
                float* t0 = wtile + ke;
                // clamp-aliased rows only lose adds on garbage rows 0/11
                float a0 = t0[ro[0]], a1 = t0[ro[1]], a2 = t0[ro[2]],
                      a3 = t0[ro[3]], a4 = t0[ro[4]];
                float b0 = t0[ro[0] + 64], b1 = t0[ro[1] + 64], b2 = t0[ro[2] + 64],
                      b3 = t0[ro[3] + 64], b4 = t0[ro[4] + 64];
                a0 = fmaf(dxq[0], dyq[0], a0); b0 = fmaf(dxq[1], dyq[0], b0);
                a1 = fmaf(dxq[0], dyq[1], a1); b1 = fmaf(dxq[1], dyq[1], b1);
                a2 = fmaf(dxq[0], dyq[2], a2); b2 = fmaf(dxq[1], dyq[2], b2);
                a3 = fmaf(dxq[0], dyq[3], a3); b3 = fmaf(dxq[1], dyq[3], b3);
                a4 = fmaf(dxq[0], dyq[4], a4); b4 = fmaf(dxq[1], dyq[4], b4);
                t0[ro[0]] = a0; t0[ro[1]] = a1; t0[ro[2]] = a2;
                t0[ro[3]] = a3; t0[ro[4]] = a4;
                t0[ro[0] + 64] = b0; t0[ro[1] + 64] = b1; t0[ro[2] + 64] = b2;
                t0[ro[3] + 64] = b3; t0[ro[4] + 64] = b4;
            }
            asm volatile("s_waitcnt lgkmcnt(0)" ::: "memory");
        }
    }
    __syncthreads();

    // fused 4-way tile merge + quantization reduce; owned rows = tile rows 1..10
    if (tid < YB_ROWS * W) {
        int rl = tid >> 1, cl = tid & 1;
        int off = (rl + 1) * (W * 64) + cl * 64;
        float tot2 = 0.f, halves = 0.f;
#pragma unroll
        for (int ck = 0; ck < NCK; ++ck) {
            float q = 0.f;
#pragma unroll
            for (int h2 = 0; h2 < 2; ++h2) {
                float4 d = make_float4(0.f, 0.f, 0.f, 0.f);
#pragma unroll
                for (int w2 = 0; w2 < 4; ++w2) {
                    float4 e = *(const float4*)(sh + w2 * TILE_F + off + ck * 8 + h2 * 4);
                    d.x += e.x; d.y += e.y; d.z += e.z; d.w += e.w;
                }
                tot2 += d.x + d.y + d.z + d.w;
                q += ceilf(d.x * 0.25f) + ceilf(d.y * 0.25f) +
                     ceilf(d.z * 0.25f) + ceilf(d.w * 0.25f);
            }
            halves += ceilf(0.5f * q);
        }
        float slices = ceilf(0.5f * halves);
        scale[(c0 + cl) * NBY + y0 + rl] = (tot2 > 0.f) ? (slices / fmaxf(tot2, 1e-12f)) : 0.f;
    }
}

__global__ void ff_gather(const float* __restrict__ pos,
                          const float* __restrict__ nsx,
                          const float* __restrict__ nsy,
                          const int* __restrict__ fi,
                          const float* __restrict__ scale,
                          float* __restrict__ out) {
    int f = blockIdx.x * blockDim.x + threadIdx.x;
    if (f >= NUM_FLOPS) return;
    int i = fi[f];
    float cx = pos[i] + 0.5f * nsx[i];
    float cy = pos[NUM_NODES + i] + 0.5f * nsy[i];
    int bx0 = (int)floorf(cx); bx0 = bx0 < 0 ? 0 : (bx0 > NBX - 1 ? NBX - 1 : bx0);
    int by0 = (int)floorf(cy); by0 = by0 < 0 ? 0 : (by0 > NBY - 1 ? NBY - 1 : by0);
    out[i] = scale[bx0 * NBY + by0];
}

extern "C" void kernel_launch(void* const* d_in, const int* in_sizes, int n_in,
                              void* d_out, int out_size, void* d_ws, size_t ws_size,
                              hipStream_t stream) {
    const float* pos = (const float*)d_in[0];
    const float* nsx = (const float*)d_in[1];
    const float* nsy = (const float*)d_in[2];
    const int*   fi  = (const int*)d_in[3];
    const int*   cs  = (const int*)d_in[4];
    float* out = (float*)d_out;

    float* scale  = (float*)d_ws;
    int*   colcnt = (int*)(scale + NBINS);
    int*   bstart = colcnt + NBX;
    int*   bcnt   = bstart + NBX * NYB;
    Rec12* rec    = (Rec12*)(bcnt + NBX * NYB);

    hipMemsetAsync(colcnt, 0, NBX * sizeof(int), stream);

    ff_fill<<<P1_BLOCKS, 1024, 0, stream>>>(pos, nsx, nsy, fi, cs, colcnt, rec, out);
    ff_sort<<<NBX, 1024, 0, stream>>>(colcnt, rec, bstart, bcnt);
    ff_main<<<dim3(NBX / W, NYB), 256, 0, stream>>>(bstart, bcnt, rec, scale);
    ff_gather<<<(NUM_FLOPS + 255) / 256, 256, 0, stream>>>(pos, nsx, nsy, fi, scale, out);
}